// Round 20
// baseline (76.851 us; speedup 1.0000x reference)
//
#include <hip/hip_runtime.h>

#define NE  5
#define V   25
#define NT  300
#define NC  12
#define CO  64
#define WPB 4
#define GX  38          // 38*4 = 152 wave-tasks; 150 t-pairs (2 idle)

typedef float f4 __attribute__((ext_vector_type(4)));

// intra-wave LDS ordering: drain this wave's LDS ops + pin compiler ordering.
#define WSYNC() do { asm volatile("s_waitcnt lgkmcnt(0)" ::: "memory"); \
                     __builtin_amdgcn_sched_barrier(0); } while (0)

// select w if bit e of m set, else +0.0
__device__ __forceinline__ float hsel(unsigned m, int e, float w) {
    int s = ((int)(m << (31 - e))) >> 31;
    return __int_as_float(__float_as_int(w) & s);
}

// per-wave scratch float offsets (rows 28 floats = 112B)
#define OW   0      // W[8][28]   rows 0-4 edge w, rows 5-7 feat
#define ODV  224    // DV[5][28]
#define OB   504    // B[3][5][28]   (c,i,u)        (OG slot 364 now unused)
#define OFP  924    // FP[15][28]    (k=3i+c, e)
#define OST  1344   // ST rows: swizzled, see STROW
#define SCRF 2364   // floats per wave (16B mult; max STROW+16 = 2364)

// bank-spread ST row address (16B-granular, f4-safe)
#define STROW(r) (OST + (r)*20 + (((r) >> 3) & 7)*4)

__global__ __launch_bounds__(256, 4) void hyper_main(
    const float* __restrict__ x,
    const float* __restrict__ h0, const float* __restrict__ h1,
    const float* __restrict__ h2, const float* __restrict__ h3,
    const float* __restrict__ h4,
    const float* __restrict__ wmlp, const float* __restrict__ bmlp,
    float* __restrict__ out)
{
    __shared__ unsigned RM[125];   // row masks [i*25+v] over e
    __shared__ unsigned CM[125];   // col masks [i*25+e] over u
    __shared__ float    DE[125];   // 1/degree_e
    __shared__ __align__(16) float SCR[WPB][SCRF];

    const int tid  = threadIdx.x;
    const int lane = tid & 63;
    const int wid  = tid >> 6;
    const int b    = blockIdx.y;

    // ---- block init (all branches within 256 threads) ----
    if (tid < 125) {
        int i = tid / 25, v = tid % 25;
        const float* hp = (i==0)?h0:(i==1)?h1:(i==2)?h2:(i==3)?h3:h4;
        unsigned m = 0;
        for (int e = 0; e < V; ++e) if (hp[v*V + e] != 0.f) m |= (1u << e);
        RM[tid] = m;
    } else if (tid < 250) {
        int idx = tid - 125, i = idx / 25, e = idx % 25;
        const float* hp = (i==0)?h0:(i==1)?h1:(i==2)?h2:(i==3)?h3:h4;
        unsigned m = 0; float s = 0.f;
        for (int u = 0; u < V; ++u) {
            float hv = hp[u*V + e];
            s += hv;
            if (hv != 0.f) m |= (1u << u);
        }
        CM[idx] = m;
        DE[idx] = (s != 0.f) ? __fdiv_rn(1.f, s) : 0.f;
    }
    __syncthreads();   // only block-wide barrier

    const int pp = blockIdx.x * WPB + wid;   // one t-pair per wave
    if (pp >= NT/2) return;

    float* S = SCR[wid];

    // ---- prefetch lane constants: item q = r*64+lane over 200 = 8ch x 25e ----
    const float* xb[4]; int lo[4];
    {
        #pragma unroll
        for (int r = 0; r < 4; ++r) {
            int q  = r*64 + lane;
            int qq = (q < 200) ? q : 0;
            int ch = qq / 25, e = qq % 25;
            int xc = (ch < 5) ? (ch + 6 + (ch >= 2 ? 1 : 0)) : (ch - 5);
            lo[r] = OW + ch*28 + e;
            xb[r] = x + (size_t)(b*NC + xc)*NT*V + e;
        }
    }
    const bool act3 = (lane < 8);      // r=3 valid items: q=192..199

    // prologue prefetch: t = 2*pp
    float pf0, pf1, pf2, pf3;
    {
        int t0 = 2 * pp;
        pf0 = xb[0][t0*V]; pf1 = xb[1][t0*V];
        pf2 = xb[2][t0*V]; pf3 = xb[3][t0*V];
    }

    for (int tp = 0; tp < 2; ++tp) {

        // ---- commit prefetched W ----
        S[lo[0]] = pf0; S[lo[1]] = pf1; S[lo[2]] = pf2;
        if (act3) S[lo[3]] = pf3;
        WSYNC();

        // ---- issue next-t prefetch (hidden under P1-P3 compute) ----
        if (tp == 0) {
            int tn = 2*pp + 1;
            pf0 = xb[0][tn*V]; pf1 = xb[1][tn*V];
            pf2 = xb[2][tn*V]; pf3 = xb[3][tn*V];
        }

        // ---- P1: dv via mod-4 class bit-loops (bit-exact numpy association:
        // skipped terms are +0.0 adds = bitwise identity; verified R12) + B.
        // 4 independent load chains -> latency overlaps without batching. ----
        for (int r = 0; r < 2; ++r) {
            int idx = r*64 + lane;
            if (idx < 125) {
                int i = idx / 25, v = idx % 25;
                unsigned m = RM[idx];
                const float* wi = S + OW + i*28;
                float L0 = 0.f, L1 = 0.f, L2 = 0.f, L3 = 0.f;
                unsigned mm;
                mm = m & 0x00111111u;
                while (mm) { int e = __builtin_ctz(mm); mm &= mm-1; L0 = __fadd_rn(L0, wi[e]); }
                mm = m & 0x00222222u;
                while (mm) { int e = __builtin_ctz(mm); mm &= mm-1; L1 = __fadd_rn(L1, wi[e]); }
                mm = m & 0x00444444u;
                while (mm) { int e = __builtin_ctz(mm); mm &= mm-1; L2 = __fadd_rn(L2, wi[e]); }
                mm = m & 0x00888888u;
                while (mm) { int e = __builtin_ctz(mm); mm &= mm-1; L3 = __fadd_rn(L3, wi[e]); }
                float s = __fadd_rn(__fadd_rn(L0, L1), __fadd_rn(L2, L3));
                s = __fadd_rn(s, hsel(m, 24, wi[24]));
                float dvv = (s > 0.f) ? (float)(1.0 / sqrt((double)s)) : 0.f;
                S[ODV + i*28 + v] = dvv;
                float f0  = S[OW + 5*28 + v];
                float f1  = S[OW + 6*28 + v];
                float f2v = S[OW + 7*28 + v];
                S[OB + (0*5+i)*28 + v] = dvv * f0;
                S[OB + (1*5+i)*28 + v] = dvv * f1;
                S[OB + (2*5+i)*28 + v] = dvv * f2v;
            }
        }
        WSYNC();

        // ---- P2: FP[3i+c][e] = (w[e]*de[e]) * sum_u h[u,e]*B[c][i][u] ----
        // batched-prefetch bit-loop (R19); g folded inline (R12, verified).
        for (int r = 0; r < 2; ++r) {
            int idx = r*64 + lane;
            if (idx < 125) {
                int i = idx / 25, e = idx % 25;
                unsigned m = CM[idx];
                const float* bp = S + OB + i*28;
                float a0 = 0.f, a1 = 0.f, a2 = 0.f;
                while (m) {
                    int u[5]; bool vl[5];
                    #pragma unroll
                    for (int j = 0; j < 5; ++j) {
                        vl[j] = (m != 0u);
                        u[j]  = __builtin_ctz(m | 0x02000000u); // empty -> 25 (in-row pad)
                        m &= m - 1;
                    }
                    float b0[5], b1[5], b2[5];
                    #pragma unroll
                    for (int j = 0; j < 5; ++j) {
                        b0[j] = bp[u[j]];
                        b1[j] = bp[140 + u[j]];
                        b2[j] = bp[280 + u[j]];
                    }
                    #pragma unroll
                    for (int j = 0; j < 5; ++j) {
                        a0 += vl[j] ? b0[j] : 0.f;
                        a1 += vl[j] ? b1[j] : 0.f;
                        a2 += vl[j] ? b2[j] : 0.f;
                    }
                }
                float gg = S[OW + i*28 + e] * DE[idx];
                S[OFP + (i*3+0)*28 + e] = a0 * gg;
                S[OFP + (i*3+1)*28 + e] = a1 * gg;
                S[OFP + (i*3+2)*28 + e] = a2 * gg;
            }
        }
        WSYNC();

        // ---- P3: ST[tp*25+v][3i+c] = dv * sum_e h[v,e]*FP[3i+c][e] ----
        for (int r = 0; r < 2; ++r) {
            int idx = r*64 + lane;
            if (idx < 125) {
                int i = idx / 25, v = idx % 25;
                unsigned m = RM[idx];
                const float* fp = S + OFP + i*3*28;
                float a0 = 0.f, a1 = 0.f, a2 = 0.f;
                while (m) {
                    int u[5]; bool vl[5];
                    #pragma unroll
                    for (int j = 0; j < 5; ++j) {
                        vl[j] = (m != 0u);
                        u[j]  = __builtin_ctz(m | 0x02000000u);
                        m &= m - 1;
                    }
                    float b0[5], b1[5], b2[5];
                    #pragma unroll
                    for (int j = 0; j < 5; ++j) {
                        b0[j] = fp[u[j]];
                        b1[j] = fp[28 + u[j]];
                        b2[j] = fp[56 + u[j]];
                    }
                    #pragma unroll
                    for (int j = 0; j < 5; ++j) {
                        a0 += vl[j] ? b0[j] : 0.f;
                        a1 += vl[j] ? b1[j] : 0.f;
                        a2 += vl[j] ? b2[j] : 0.f;
                    }
                }
                float dd = S[ODV + i*28 + v];
                float* st = S + STROW(tp*25 + v) + i*3;
                st[0] = a0 * dd; st[1] = a1 * dd; st[2] = a2 * dd;
            }
        }
        WSYNC();
    }

    // ---- P4: MLP + relu. Scalar per-o chain (R17), swizzled ST rows ----
    if (lane < 50) {
        const float* st = S + STROW(lane);
        f4 s0 = *(const f4*)(st+0), s1 = *(const f4*)(st+4),
           s2 = *(const f4*)(st+8), s3 = *(const f4*)(st+12);
        s3.w = 0.f;
        float* ob = out + (size_t)b*CO*7500 + (size_t)pp*50 + lane;
        #pragma unroll 8
        for (int o = 0; o < CO; ++o) {
            const float* wm = wmlp + o*15;   // wave-uniform -> scalar loads
            float a = bmlp[o];
            a = fmaf(wm[ 0], s0.x, a); a = fmaf(wm[ 1], s0.y, a);
            a = fmaf(wm[ 2], s0.z, a); a = fmaf(wm[ 3], s0.w, a);
            a = fmaf(wm[ 4], s1.x, a); a = fmaf(wm[ 5], s1.y, a);
            a = fmaf(wm[ 6], s1.z, a); a = fmaf(wm[ 7], s1.w, a);
            a = fmaf(wm[ 8], s2.x, a); a = fmaf(wm[ 9], s2.y, a);
            a = fmaf(wm[10], s2.z, a); a = fmaf(wm[11], s2.w, a);
            a = fmaf(wm[12], s3.x, a); a = fmaf(wm[13], s3.y, a);
            a = fmaf(wm[14], s3.z, a);
            __builtin_nontemporal_store(fmaxf(a, 0.f), ob + (size_t)o*7500);
        }
    }
}

extern "C" void kernel_launch(void* const* d_in, const int* in_sizes, int n_in,
                              void* d_out, int out_size, void* d_ws, size_t ws_size,
                              hipStream_t stream) {
    const float* x    = (const float*)d_in[0];
    const float* h0   = (const float*)d_in[1];
    const float* h1   = (const float*)d_in[2];
    const float* h2   = (const float*)d_in[3];
    const float* h3   = (const float*)d_in[4];
    const float* h4   = (const float*)d_in[5];
    const float* wmlp = (const float*)d_in[6];
    const float* bmlp = (const float*)d_in[7];
    float* out = (float*)d_out;

    hyper_main<<<dim3(GX, 64, 1), dim3(256,1,1), 0, stream>>>(
        x, h0, h1, h2, h3, h4, wmlp, bmlp, out);
}